// Round 5
// baseline (1504.376 us; speedup 1.0000x reference)
//
#include <hip/hip_runtime.h>
#include <math.h>

#define NN 6144
#define DD 512
#define CAP 128

typedef __bf16 bf16_t;
typedef __bf16 bf16x8 __attribute__((ext_vector_type(8)));
typedef unsigned short u16x8 __attribute__((ext_vector_type(8)));
typedef float f32x4 __attribute__((ext_vector_type(4)));
typedef unsigned u32x4 __attribute__((ext_vector_type(4)));

__device__ __forceinline__ float bf2f(unsigned short u) {
    unsigned v = ((unsigned)u) << 16;
    return __builtin_bit_cast(float, v);
}
__device__ __forceinline__ unsigned short f2bf(float f) {
    unsigned u = __builtin_bit_cast(unsigned, f);
    u += 0x7fffu + ((u >> 16) & 1u);   // round-to-nearest-even
    return (unsigned short)(u >> 16);
}
__device__ __forceinline__ float sigmoidf_(float z) { return 1.0f / (1.0f + expf(-z)); }

// =========== d1: k_w — wt transpose (blocks 0..127) + w_sl/w_sr (blocks 128..255) ===========
__global__ __launch_bounds__(256) void k_w(const float* __restrict__ Wsa,
                                           const float* __restrict__ Wg,
                                           const float* __restrict__ a_sa,
                                           unsigned short* __restrict__ wt,
                                           float* __restrict__ wsl, float* __restrict__ wsr) {
    __shared__ float s[64][65];
    int bid = blockIdx.x;
    int wave = threadIdx.x >> 6, lane = threadIdx.x & 63;
    if (bid < 128) {
        int n0 = (bid & 15) * 64;
        int k0 = (bid >> 4) * 64;
        int tx = threadIdx.x & 63, ty = threadIdx.x >> 6;
        const float* src = (n0 < 512) ? Wsa : Wg;
        int nn0 = n0 & 511;
#pragma unroll
        for (int kk = 0; kk < 64; kk += 4)
            s[kk + ty][tx] = src[(size_t)(k0 + kk + ty) * 512 + nn0 + tx];
        __syncthreads();
#pragma unroll
        for (int nn = 0; nn < 64; nn += 4)
            wt[(size_t)(n0 + nn + ty) * 512 + k0 + tx] = f2bf(s[tx][nn + ty]);
    } else {
        // w_sl[k] = sum_n Wsa[k][n]*a_sa[n];  w_sr[k] = sum_n Wsa[k][n]*a_sa[512+n]
        int k = (bid - 128) * 4 + wave;         // 0..511
        int n0 = lane * 8;
        const float* wr = Wsa + (size_t)k * 512 + n0;
        float4 w0 = *(const float4*)wr, w1 = *(const float4*)(wr + 4);
        float4 l0 = *(const float4*)(a_sa + n0), l1 = *(const float4*)(a_sa + n0 + 4);
        float4 r0 = *(const float4*)(a_sa + 512 + n0), r1 = *(const float4*)(a_sa + 512 + n0 + 4);
        float sl_ = w0.x*l0.x + w0.y*l0.y + w0.z*l0.z + w0.w*l0.w
                  + w1.x*l1.x + w1.y*l1.y + w1.z*l1.z + w1.w*l1.w;
        float sr_ = w0.x*r0.x + w0.y*r0.y + w0.z*r0.z + w0.w*r0.w
                  + w1.x*r1.x + w1.y*r1.y + w1.z*r1.z + w1.w*r1.w;
#pragma unroll
        for (int off = 32; off; off >>= 1) { sl_ += __shfl_down(sl_, off); sr_ += __shfl_down(sr_, off); }
        if (lane == 0) { wsl[k] = sl_; wsr[k] = sr_; }
    }
}

// =========== d2: k_mid — even blocks: MFMA GEMM tile; odd blocks: per-row projections ===========
__global__ __launch_bounds__(256) void k_mid(const float* __restrict__ x,
                                             const bf16_t* __restrict__ wt,
                                             const float* __restrict__ Wa,
                                             const float* __restrict__ Wb,
                                             const float* __restrict__ wsl,
                                             const float* __restrict__ wsr,
                                             unsigned short* __restrict__ h,
                                             unsigned short* __restrict__ g,
                                             float* __restrict__ xal, float* __restrict__ xar,
                                             float* __restrict__ xbl, float* __restrict__ xbr,
                                             float* __restrict__ sl, float* __restrict__ sr) {
    int bid = blockIdx.x;
    int wave = threadIdx.x >> 6, lane = threadIdx.x & 63;
    if ((bid & 1) == 0) {
        // ---- GEMM tile: 64 rows x 64 cols, MFMA 16x16x32, A cvt in-register ----
        int tt = bid >> 1;                        // 0..1535
        int row0 = (tt % (NN / 64)) * 64 + wave * 16;
        int col0 = (tt / (NN / 64)) * 64;
        int lr = lane & 15;
        int kg = (lane >> 4) * 8;

        f32x4 acc[4] = {{0,0,0,0},{0,0,0,0},{0,0,0,0},{0,0,0,0}};
        const float* ap = x + (size_t)(row0 + lr) * DD + kg;
        const bf16_t* bp = wt + (size_t)(col0 + lr) * DD + kg;

        for (int k0 = 0; k0 < DD; k0 += 32) {
            float4 a0 = *(const float4*)(ap + k0);
            float4 a1 = *(const float4*)(ap + k0 + 4);
            u16x8 au;
            au[0] = f2bf(a0.x); au[1] = f2bf(a0.y); au[2] = f2bf(a0.z); au[3] = f2bf(a0.w);
            au[4] = f2bf(a1.x); au[5] = f2bf(a1.y); au[6] = f2bf(a1.z); au[7] = f2bf(a1.w);
            bf16x8 a = __builtin_bit_cast(bf16x8, au);
#pragma unroll
            for (int n = 0; n < 4; n++) {
                bf16x8 b = *(const bf16x8*)(bp + (size_t)n * 16 * DD + k0);
                acc[n] = __builtin_amdgcn_mfma_f32_16x16x32_bf16(a, b, acc[n], 0, 0, 0);
            }
        }
        int dcol = lane & 15;
        int dr0 = (lane >> 4) * 4;
#pragma unroll
        for (int n = 0; n < 4; n++) {
            int col = col0 + n * 16 + dcol;
            unsigned short* dst = (col < 512) ? h : g;
            int cc = col & 511;
#pragma unroll
            for (int rr = 0; rr < 4; rr++) {
                int mr = row0 + dr0 + rr;
                dst[(size_t)mr * 512 + cc] = f2bf(acc[n][rr]);
            }
        }
    } else {
        // ---- projections: rows pid*4+wave; 6 dot products vs x-row ----
        int pid = bid >> 1;                       // 0..1535
        int row = pid * 4 + wave;
        int k0 = lane * 8;
        const float* xr_ = x + (size_t)row * DD + k0;
        float4 v0 = *(const float4*)xr_;
        float4 v1 = *(const float4*)(xr_ + 4);
        float xv[8] = {v0.x, v0.y, v0.z, v0.w, v1.x, v1.y, v1.z, v1.w};
        float d[6] = {0, 0, 0, 0, 0, 0};
        const float* srcs[6] = {Wa + k0, Wa + 512 + k0, Wb + k0, Wb + 512 + k0, wsl + k0, wsr + k0};
#pragma unroll
        for (int q = 0; q < 6; q++) {
            float4 w0 = *(const float4*)srcs[q];
            float4 w1 = *(const float4*)(srcs[q] + 4);
            float wv[8] = {w0.x, w0.y, w0.z, w0.w, w1.x, w1.y, w1.z, w1.w};
#pragma unroll
            for (int j = 0; j < 8; j++) d[q] += xv[j] * wv[j];
        }
#pragma unroll
        for (int off = 32; off; off >>= 1)
#pragma unroll
            for (int q = 0; q < 6; q++) d[q] += __shfl_down(d[q], off);
        if (lane == 0) {
            xal[row] = d[0]; xar[row] = d[1];
            xbl[row] = d[2]; xbr[row] = d[3];
            sl[row] = d[4]; sr[row] = d[5];
        }
    }
}

// =========== d3: k_scan — nt half-row scan + completion-triggered inline final ===========
__global__ __launch_bounds__(256) void k_scan(const float* __restrict__ adjA,
                                              const float* __restrict__ adjB,
                                              const unsigned short* __restrict__ h,
                                              const unsigned short* __restrict__ g,
                                              const float* __restrict__ sl, const float* __restrict__ sr,
                                              const float* __restrict__ xal, const float* __restrict__ xar,
                                              const float* __restrict__ xbl, const float* __restrict__ xbr,
                                              const float* __restrict__ ba, const float* __restrict__ bb,
                                              const float* __restrict__ bias,
                                              int* __restrict__ idxA, int* __restrict__ idxB,
                                              int* __restrict__ cntA, int* __restrict__ cntB,
                                              int* __restrict__ done,
                                              float* __restrict__ out) {
    int bid = blockIdx.x;
    int wave = threadIdx.x >> 6, lane = threadIdx.x & 63;
    int gw = bid * 4 + wave;                  // 0..24575
    int row = gw >> 1;                        // 0..12287
    int half = gw & 1;
    int which = row >= NN;
    int r = which ? row - NN : row;
    const float* adj = which ? adjB : adjA;
    int* idx = (which ? idxB : idxA) + (size_t)r * CAP;
    int* cnt = which ? cntB : cntA;

    // ---- scan half-row: 12 nt uint4 loads, register bitmask, prefix-sum, scatter ----
    const u32x4* arow = (const u32x4*)(adj + (size_t)r * NN) + half * 768 + lane;
    unsigned long long m = 0;
#pragma unroll
    for (int j = 0; j < 12; j++) {
        u32x4 v = __builtin_nontemporal_load(arow + j * 64);
        unsigned long long bits =
            (unsigned long long)(v[0] != 0u) |
            ((unsigned long long)(v[1] != 0u) << 1) |
            ((unsigned long long)(v[2] != 0u) << 2) |
            ((unsigned long long)(v[3] != 0u) << 3);
        m |= bits << (j * 4);
    }
    int c = (int)__popcll(m);
    int p = c;
#pragma unroll
    for (int off = 1; off < 64; off <<= 1) {
        int t = __shfl_up(p, off);
        if (lane >= off) p += t;
    }
    int total = __shfl(p, 63);
    int base = 0;
    if (lane == 0) base = atomicAdd(&cnt[r], total);
    base = __shfl(base, 0);
    int pos = base + p - c;
    while (m) {
        int b = __ffsll((long long)m) - 1;
        m &= m - 1;
        int col = ((half * 768) + ((b >> 2) * 64) + lane) * 4 + (b & 3);
        if (pos < CAP) idx[pos] = col;
        pos++;
    }

    // ---- completion counter: 4 waves per output row (A half0/1, B half0/1) ----
    __threadfence();                           // release: make idx/cnt visible device-wide
    int old = 0;
    if (lane == 0) old = atomicAdd(&done[r], 1);
    old = __shfl(old, 0);
    if (old != 3) return;
    __threadfence();                           // acquire: see all other waves' idx/cnt

    // ---- inline final for row i = r (one wave, lane handles dims lane*8..+7) ----
    int i = r;
    int cA = cntA[i]; cA = cA > CAP ? CAP : cA;
    int cB = cntB[i]; cB = cB > CAP ? CAP : cB;
    const int* ia = idxA + (size_t)i * CAP;
    const int* ib = idxB + (size_t)i * CAP;

    int j0 = (lane < cA) ? ia[lane] : 0;
    int j1 = (lane + 64 < cA) ? ia[lane + 64] : 0;
    int jb0 = (lane < cB) ? ib[lane] : 0;
    int jb1 = (lane + 64 < cB) ? ib[lane + 64] : 0;

    float sli = sl[i];
    float w0 = 0.f, w1 = 0.f, psum = 0.f, gas = 0.f, gbs = 0.f;
    if (lane < cA) {
        float s = sli + sr[j0];
        float lr = s > 0.f ? s : 0.01f * s;
        w0 = expf(-lr); psum += w0; gas += xal[j0];
    }
    if (lane + 64 < cA) {
        float s = sli + sr[j1];
        float lr = s > 0.f ? s : 0.01f * s;
        w1 = expf(-lr); psum += w1; gas += xal[j1];
    }
    if (lane < cB) gbs += xbl[jb0];
    if (lane + 64 < cB) gbs += xbl[jb1];
#pragma unroll
    for (int off = 1; off < 64; off <<= 1) {
        psum += __shfl_xor(psum, off);
        gas += __shfl_xor(gas, off);
        gbs += __shfl_xor(gbs, off);
    }
    float inv = 1.f / (psum + 1e-5f);
    float ga = sigmoidf_(gas + xar[i] + ba[0]);
    float gb = sigmoidf_(gbs + xbr[i] + bb[0]);

    const u32x4* h4 = (const u32x4*)h;
    const u32x4* g4 = (const u32x4*)g;
    float accA[8] = {0, 0, 0, 0, 0, 0, 0, 0};
    float accB[8] = {0, 0, 0, 0, 0, 0, 0, 0};
    for (int t = 0; t < cA; t++) {
        int j = __shfl(t < 64 ? j0 : j1, t & 63);
        float wt_ = __shfl(t < 64 ? w0 : w1, t & 63);
        u32x4 hv = h4[(size_t)j * 64 + lane];
#pragma unroll
        for (int q = 0; q < 4; q++) {
            accA[2 * q]     += wt_ * bf2f((unsigned short)(hv[q] & 0xffff));
            accA[2 * q + 1] += wt_ * bf2f((unsigned short)(hv[q] >> 16));
        }
    }
    for (int t = 0; t < cB; t++) {
        int j = __shfl(t < 64 ? jb0 : jb1, t & 63);
        u32x4 gv = g4[(size_t)j * 64 + lane];
#pragma unroll
        for (int q = 0; q < 4; q++) {
            accB[2 * q]     += bf2f((unsigned short)(gv[q] & 0xffff));
            accB[2 * q + 1] += bf2f((unsigned short)(gv[q] >> 16));
        }
    }
    int d0 = lane * 8;
    float4 bs0 = *(const float4*)(bias + d0);
    float4 bs1 = *(const float4*)(bias + d0 + 4);
    float bv[8] = {bs0.x, bs0.y, bs0.z, bs0.w, bs1.x, bs1.y, bs1.z, bs1.w};
    float ov[8];
#pragma unroll
    for (int q = 0; q < 8; q++)
        ov[q] = sigmoidf_(ga * (accA[q] * inv) + gb * (accB[q] + bv[q]));
    float4 o0 = {ov[0], ov[1], ov[2], ov[3]};
    float4 o1 = {ov[4], ov[5], ov[6], ov[7]};
    *(float4*)(out + (size_t)i * 512 + d0) = o0;
    *(float4*)(out + (size_t)i * 512 + d0 + 4) = o1;
}

extern "C" void kernel_launch(void* const* d_in, const int* in_sizes, int n_in,
                              void* d_out, int out_size, void* d_ws, size_t ws_size,
                              hipStream_t stream) {
    const float* x    = (const float*)d_in[0];
    const float* adjA = (const float*)d_in[1];
    const float* adjB = (const float*)d_in[2];
    const float* Wsa  = (const float*)d_in[3];
    const float* a_sa = (const float*)d_in[4];
    const float* Wg   = (const float*)d_in[5];
    const float* bg   = (const float*)d_in[6];
    const float* Wa   = (const float*)d_in[7];
    const float* ba   = (const float*)d_in[8];
    const float* Wb   = (const float*)d_in[9];
    const float* bb   = (const float*)d_in[10];
    float* out = (float*)d_out;

    char* ws = (char*)d_ws;
    size_t off = 0;
    auto alloc = [&](size_t bytes) -> void* {
        void* p = ws + off;
        off += (bytes + 255) & ~(size_t)255;
        return p;
    };
    unsigned short* wt = (unsigned short*)alloc((size_t)1024 * DD * 2);
    unsigned short* h  = (unsigned short*)alloc((size_t)NN * DD * 2);
    unsigned short* g  = (unsigned short*)alloc((size_t)NN * DD * 2);
    int* idxA = (int*)alloc((size_t)NN * CAP * 4);
    int* idxB = (int*)alloc((size_t)NN * CAP * 4);
    int* cntA = (int*)alloc((size_t)NN * 4 * 3);   // cntA | cntB | done contiguous
    int* cntB = cntA + NN;
    int* done = cntA + 2 * NN;
    float* xal = (float*)alloc((size_t)NN * 4);
    float* xar = (float*)alloc((size_t)NN * 4);
    float* xbl = (float*)alloc((size_t)NN * 4);
    float* xbr = (float*)alloc((size_t)NN * 4);
    float* sl  = (float*)alloc((size_t)NN * 4);
    float* sr  = (float*)alloc((size_t)NN * 4);
    float* wsl = (float*)alloc((size_t)DD * 4);
    float* wsr = (float*)alloc((size_t)DD * 4);

    // zero counters (graph-capture-safe)
    hipMemsetAsync(cntA, 0, (size_t)NN * 4 * 3, stream);
    // d1: W^T (bf16) + w_sl/w_sr
    k_w<<<256, 256, 0, stream>>>(Wsa, Wg, a_sa, wt, wsl, wsr);
    // d2: GEMM (h,g) + projections (xal..xbr, sl, sr)
    k_mid<<<3072, 256, 0, stream>>>(x, (const bf16_t*)wt, Wa, Wb, wsl, wsr,
                                    h, g, xal, xar, xbl, xbr, sl, sr);
    // d3: nt scan + completion-triggered inline final
    k_scan<<<NN, 256, 0, stream>>>(adjA, adjB, h, g, sl, sr, xal, xar, xbl, xbr,
                                   ba, bb, bg, idxA, idxB, cntA, cntB, done, out);
}

// Round 6
// 172.296 us; speedup vs baseline: 8.7313x; 8.7313x over previous
//
#include <hip/hip_runtime.h>
#include <math.h>

#define NN 6144
#define DD 512
#define CAP 128

typedef __bf16 bf16_t;
typedef __bf16 bf16x8 __attribute__((ext_vector_type(8)));
typedef unsigned short u16x8 __attribute__((ext_vector_type(8)));
typedef float f32x4 __attribute__((ext_vector_type(4)));
typedef unsigned u32x4 __attribute__((ext_vector_type(4)));

__device__ __forceinline__ float bf2f(unsigned short u) {
    unsigned v = ((unsigned)u) << 16;
    return __builtin_bit_cast(float, v);
}
__device__ __forceinline__ unsigned short f2bf(float f) {
    unsigned u = __builtin_bit_cast(unsigned, f);
    u += 0x7fffu + ((u >> 16) & 1u);   // round-to-nearest-even
    return (unsigned short)(u >> 16);
}
__device__ __forceinline__ float sigmoidf_(float z) { return 1.0f / (1.0f + expf(-z)); }

// =========== d1: k_prep — wt transpose (blocks 0..127) + w_sl/w_sr (blocks 128..255) ===========
__global__ __launch_bounds__(256) void k_prep(const float* __restrict__ Wsa,
                                              const float* __restrict__ Wg,
                                              const float* __restrict__ a_sa,
                                              unsigned short* __restrict__ wt,
                                              float* __restrict__ wsl, float* __restrict__ wsr) {
    __shared__ float s[64][65];
    int bid = blockIdx.x;
    int wave = threadIdx.x >> 6, lane = threadIdx.x & 63;
    if (bid < 128) {
        int n0 = (bid & 15) * 64;
        int k0 = (bid >> 4) * 64;
        int tx = threadIdx.x & 63, ty = threadIdx.x >> 6;
        const float* src = (n0 < 512) ? Wsa : Wg;
        int nn0 = n0 & 511;
#pragma unroll
        for (int kk = 0; kk < 64; kk += 4)
            s[kk + ty][tx] = src[(size_t)(k0 + kk + ty) * 512 + nn0 + tx];
        __syncthreads();
#pragma unroll
        for (int nn = 0; nn < 64; nn += 4)
            wt[(size_t)(n0 + nn + ty) * 512 + k0 + tx] = f2bf(s[tx][nn + ty]);
    } else {
        // w_sl[k] = sum_n Wsa[k][n]*a_sa[n];  w_sr[k] = sum_n Wsa[k][n]*a_sa[512+n]
        int k = (bid - 128) * 4 + wave;         // 0..511
        int n0 = lane * 8;
        const float* wr = Wsa + (size_t)k * 512 + n0;
        float4 w0 = *(const float4*)wr, w1 = *(const float4*)(wr + 4);
        float4 l0 = *(const float4*)(a_sa + n0), l1 = *(const float4*)(a_sa + n0 + 4);
        float4 r0 = *(const float4*)(a_sa + 512 + n0), r1 = *(const float4*)(a_sa + 512 + n0 + 4);
        float sl_ = w0.x*l0.x + w0.y*l0.y + w0.z*l0.z + w0.w*l0.w
                  + w1.x*l1.x + w1.y*l1.y + w1.z*l1.z + w1.w*l1.w;
        float sr_ = w0.x*r0.x + w0.y*r0.y + w0.z*r0.z + w0.w*r0.w
                  + w1.x*r1.x + w1.y*r1.y + w1.z*r1.z + w1.w*r1.w;
#pragma unroll
        for (int off = 32; off; off >>= 1) { sl_ += __shfl_down(sl_, off); sr_ += __shfl_down(sr_, off); }
        if (lane == 0) { wsl[k] = sl_; wsr[k] = sr_; }
    }
}

// ===== d2: k_fused — {PURE-STREAM scan -> bitmask} + {MFMA GEMM} + {projections} =====
// blocks [0,7680): bid%5<4 -> scan (4 waves x half-row, mask store only); bid%5==4 -> GEMM.
// blocks [7680,9216): per-row 6-dot projections (xal,xar,xbl,xbr,sl,sr).
__global__ __launch_bounds__(256) void k_fused(const float* __restrict__ x,
                                               const bf16_t* __restrict__ wt,
                                               const float* __restrict__ adjA,
                                               const float* __restrict__ adjB,
                                               const float* __restrict__ Wa,
                                               const float* __restrict__ Wb,
                                               const float* __restrict__ wsl,
                                               const float* __restrict__ wsr,
                                               unsigned long long* __restrict__ maskbuf,
                                               unsigned short* __restrict__ h,
                                               unsigned short* __restrict__ g,
                                               float* __restrict__ xal, float* __restrict__ xar,
                                               float* __restrict__ xbl, float* __restrict__ xbr,
                                               float* __restrict__ sl, float* __restrict__ sr) {
    int bid = blockIdx.x;
    int wave = threadIdx.x >> 6, lane = threadIdx.x & 63;
    if (bid < 7680) {
        int grp = bid % 5;
        if (grp < 4) {
            // ---- pure-stream scan: 12 coalesced uint4 loads -> 48-bit mask -> 1 store ----
            int sid = (bid / 5) * 4 + grp;        // 0..6143
            int gw = sid * 4 + wave;              // 0..24575
            int row = gw >> 1;                    // 0..12287 (A rows then B rows)
            int half = gw & 1;
            int which = row >= NN;
            int r = which ? row - NN : row;
            const float* adj = which ? adjB : adjA;
            const u32x4* arow = (const u32x4*)(adj + (size_t)r * NN) + half * 768 + lane;
            u32x4 v[12];
#pragma unroll
            for (int j = 0; j < 12; j++) v[j] = arow[j * 64];
            unsigned long long m = 0;
#pragma unroll
            for (int j = 0; j < 12; j++) {
                unsigned long long bits =
                    (unsigned long long)(v[j][0] != 0u) |
                    ((unsigned long long)(v[j][1] != 0u) << 1) |
                    ((unsigned long long)(v[j][2] != 0u) << 2) |
                    ((unsigned long long)(v[j][3] != 0u) << 3);
                m |= bits << (j * 4);
            }
            maskbuf[(size_t)gw * 64 + lane] = m;
        } else {
            // ---- GEMM tile: 64 rows x 64 cols, MFMA 16x16x32, A cvt in-register ----
            int tt = bid / 5;                     // 0..1535
            int row0 = (tt % (NN / 64)) * 64 + wave * 16;
            int col0 = (tt / (NN / 64)) * 64;
            int lr = lane & 15;
            int kg = (lane >> 4) * 8;

            f32x4 acc[4] = {{0,0,0,0},{0,0,0,0},{0,0,0,0},{0,0,0,0}};
            const float* ap = x + (size_t)(row0 + lr) * DD + kg;
            const bf16_t* bp = wt + (size_t)(col0 + lr) * DD + kg;

            for (int k0 = 0; k0 < DD; k0 += 32) {
                float4 a0 = *(const float4*)(ap + k0);
                float4 a1 = *(const float4*)(ap + k0 + 4);
                u16x8 au;
                au[0] = f2bf(a0.x); au[1] = f2bf(a0.y); au[2] = f2bf(a0.z); au[3] = f2bf(a0.w);
                au[4] = f2bf(a1.x); au[5] = f2bf(a1.y); au[6] = f2bf(a1.z); au[7] = f2bf(a1.w);
                bf16x8 a = __builtin_bit_cast(bf16x8, au);
#pragma unroll
                for (int n = 0; n < 4; n++) {
                    bf16x8 b = *(const bf16x8*)(bp + (size_t)n * 16 * DD + k0);
                    acc[n] = __builtin_amdgcn_mfma_f32_16x16x32_bf16(a, b, acc[n], 0, 0, 0);
                }
            }
            int dcol = lane & 15;
            int dr0 = (lane >> 4) * 4;
#pragma unroll
            for (int n = 0; n < 4; n++) {
                int col = col0 + n * 16 + dcol;
                unsigned short* dst = (col < 512) ? h : g;
                int cc = col & 511;
#pragma unroll
                for (int rr = 0; rr < 4; rr++) {
                    int mr = row0 + dr0 + rr;
                    dst[(size_t)mr * 512 + cc] = f2bf(acc[n][rr]);
                }
            }
        }
    } else {
        // ---- projections: rows pid*4+wave; 6 dot products vs x-row ----
        int pid = bid - 7680;                     // 0..1535
        int row = pid * 4 + wave;
        int k0 = lane * 8;
        const float* xr_ = x + (size_t)row * DD + k0;
        float4 v0 = *(const float4*)xr_;
        float4 v1 = *(const float4*)(xr_ + 4);
        float xv[8] = {v0.x, v0.y, v0.z, v0.w, v1.x, v1.y, v1.z, v1.w};
        float d[6] = {0, 0, 0, 0, 0, 0};
        const float* srcs[6] = {Wa + k0, Wa + 512 + k0, Wb + k0, Wb + 512 + k0, wsl + k0, wsr + k0};
#pragma unroll
        for (int q = 0; q < 6; q++) {
            float4 w0 = *(const float4*)srcs[q];
            float4 w1 = *(const float4*)(srcs[q] + 4);
            float wv[8] = {w0.x, w0.y, w0.z, w0.w, w1.x, w1.y, w1.z, w1.w};
#pragma unroll
            for (int j = 0; j < 8; j++) d[q] += xv[j] * wv[j];
        }
#pragma unroll
        for (int off = 32; off; off >>= 1)
#pragma unroll
            for (int q = 0; q < 6; q++) d[q] += __shfl_down(d[q], off);
        if (lane == 0) {
            xal[row] = d[0]; xar[row] = d[1];
            xbl[row] = d[2]; xbr[row] = d[3];
            sl[row] = d[4]; sr[row] = d[5];
        }
    }
}

// ===== d3: k_final — mask extraction + gates + attention normalize + gathers + epilogue =====
__global__ __launch_bounds__(256) void k_final(
    const unsigned long long* __restrict__ maskbuf,
    const unsigned short* __restrict__ h, const unsigned short* __restrict__ g,
    const float* __restrict__ sl, const float* __restrict__ sr,
    const float* __restrict__ xal, const float* __restrict__ xar,
    const float* __restrict__ xbl, const float* __restrict__ xbr,
    const float* __restrict__ ba, const float* __restrict__ bb,
    const float* __restrict__ bias, float* __restrict__ out) {
    int i = blockIdx.x;
    int tid = threadIdx.x;
    int wave = tid >> 6, lane = tid & 63;
    __shared__ float w[CAP];
    __shared__ int ja[CAP], jb[CAP];
    __shared__ int tot[4];
    __shared__ float s_denom, s_ga, s_gb;

    // ---- extraction: waves 0,1 = A halves 0,1; waves 2,3 = B halves 0,1 ----
    int half = wave & 1;
    int gw = (wave < 2) ? (i * 2 + half) : ((NN + i) * 2 + half);
    unsigned long long m = maskbuf[(size_t)gw * 64 + lane];
    int c = __popcll(m);
    int p = c;
#pragma unroll
    for (int off = 1; off < 64; off <<= 1) {
        int t = __shfl_up(p, off);
        if (lane >= off) p += t;
    }
    if (lane == 63) tot[wave] = p;
    __syncthreads();
    int base = (wave == 1) ? tot[0] : (wave == 3) ? tot[2] : 0;
    int pos = base + p - c;
    int* dst = (wave < 2) ? ja : jb;
    while (m) {
        int b = __ffsll((long long)m) - 1;
        m &= m - 1;
        int col = half * 3072 + (((b >> 2) * 64 + lane) << 2) + (b & 3);
        if (pos < CAP) dst[pos] = col;
        pos++;
    }
    __syncthreads();
    int cA = tot[0] + tot[1]; cA = cA > CAP ? CAP : cA;
    int cB = tot[2] + tot[3]; cB = cB > CAP ? CAP : cB;

    // ---- attention weights ----
    if (tid < cA) {
        int j = ja[tid];
        float s = sl[i] + sr[j];
        float lrelu = s > 0.f ? s : 0.01f * s;
        w[tid] = expf(-lrelu);
    }
    __syncthreads();

    if (tid < 64) {
        float p2 = 0.f, gasum = 0.f, gbsum = 0.f;
        for (int t = tid; t < cA; t += 64) { p2 += w[t]; gasum += xal[ja[t]]; }
        for (int t = tid; t < cB; t += 64) gbsum += xbl[jb[t]];
#pragma unroll
        for (int off = 32; off; off >>= 1) {
            p2 += __shfl_down(p2, off);
            gasum += __shfl_down(gasum, off);
            gbsum += __shfl_down(gbsum, off);
        }
        if (tid == 0) {
            s_denom = p2;
            s_ga = sigmoidf_(gasum + xar[i] + ba[0]);
            s_gb = sigmoidf_(gbsum + xbr[i] + bb[0]);
        }
    }
    __syncthreads();
    float inv = 1.f / (s_denom + 1e-5f);
    float ga = s_ga, gb = s_gb;

    int d0 = tid * 2;
    float a0 = 0, a1 = 0, b0 = 0, b1 = 0;
#pragma unroll 4
    for (int t = 0; t < cA; t++) {
        unsigned hv = *(const unsigned*)(h + (size_t)ja[t] * 512 + d0);
        float wt_ = w[t];
        a0 += wt_ * bf2f((unsigned short)(hv & 0xffff));
        a1 += wt_ * bf2f((unsigned short)(hv >> 16));
    }
#pragma unroll 4
    for (int t = 0; t < cB; t++) {
        unsigned gv = *(const unsigned*)(g + (size_t)jb[t] * 512 + d0);
        b0 += bf2f((unsigned short)(gv & 0xffff));
        b1 += bf2f((unsigned short)(gv >> 16));
    }
    float z0 = ga * (a0 * inv) + gb * (b0 + bias[d0]);
    float z1 = ga * (a1 * inv) + gb * (b1 + bias[d0 + 1]);
    out[(size_t)i * 512 + d0]     = sigmoidf_(z0);
    out[(size_t)i * 512 + d0 + 1] = sigmoidf_(z1);
}

extern "C" void kernel_launch(void* const* d_in, const int* in_sizes, int n_in,
                              void* d_out, int out_size, void* d_ws, size_t ws_size,
                              hipStream_t stream) {
    const float* x    = (const float*)d_in[0];
    const float* adjA = (const float*)d_in[1];
    const float* adjB = (const float*)d_in[2];
    const float* Wsa  = (const float*)d_in[3];
    const float* a_sa = (const float*)d_in[4];
    const float* Wg   = (const float*)d_in[5];
    const float* bg   = (const float*)d_in[6];
    const float* Wa   = (const float*)d_in[7];
    const float* ba   = (const float*)d_in[8];
    const float* Wb   = (const float*)d_in[9];
    const float* bb   = (const float*)d_in[10];
    float* out = (float*)d_out;

    char* ws = (char*)d_ws;
    size_t off = 0;
    auto alloc = [&](size_t bytes) -> void* {
        void* p = ws + off;
        off += (bytes + 255) & ~(size_t)255;
        return p;
    };
    unsigned short* wt = (unsigned short*)alloc((size_t)1024 * DD * 2);
    unsigned short* h  = (unsigned short*)alloc((size_t)NN * DD * 2);
    unsigned short* g  = (unsigned short*)alloc((size_t)NN * DD * 2);
    unsigned long long* maskbuf = (unsigned long long*)alloc((size_t)24576 * 64 * 8);
    float* xal = (float*)alloc((size_t)NN * 4);
    float* xar = (float*)alloc((size_t)NN * 4);
    float* xbl = (float*)alloc((size_t)NN * 4);
    float* xbr = (float*)alloc((size_t)NN * 4);
    float* sl  = (float*)alloc((size_t)NN * 4);
    float* sr  = (float*)alloc((size_t)NN * 4);
    float* wsl = (float*)alloc((size_t)DD * 4);
    float* wsr = (float*)alloc((size_t)DD * 4);

    // d1: W^T (bf16) + w_sl/w_sr
    k_prep<<<256, 256, 0, stream>>>(Wsa, Wg, a_sa, wt, wsl, wsr);
    // d2: pure-stream mask scan + GEMM + projections
    k_fused<<<9216, 256, 0, stream>>>(x, (const bf16_t*)wt, adjA, adjB, Wa, Wb, wsl, wsr,
                                      maskbuf, h, g, xal, xar, xbl, xbr, sl, sr);
    // d3: extraction + gates + attention + gathers + epilogue
    k_final<<<NN, 256, 0, stream>>>(maskbuf, h, g, sl, sr, xal, xar, xbl, xbr,
                                    ba, bb, bg, out);
}